// Round 2
// baseline (1209.942 us; speedup 1.0000x reference)
//
#include <hip/hip_runtime.h>
#include <hip/hip_bf16.h>

// QuantizedLinear: fp8-e4m3 fake-quant (dynamic per-tensor scale) of x and W,
// then out = qx @ qW^T + bias.
//
// Stage 1: amax(x), amax(w) via atomicMax on float bits.
// Stage 2: quant to SCALED bf16 (exact: <=4 mantissa bits after RNE-to-3-bit
//          mantissa rounding == reference's round(xs/lsb)*lsb). Dequant by
//          amax_x*amax_w/448^2 deferred to GEMM epilogue.
// Stage 3: GEMM 256x256 tile, BK=64 split in two 32-k phases, 8 waves (2x4),
//          double-buffered LDS (128 KiB), counted s_waitcnt vmcnt(8) (T4),
//          (row&3)<<4 XOR swizzle on 16B chunks (T2, applied to BOTH the
//          pre-swizzled global_load_lds source and the ds_read addr),
//          setprio around MFMA cluster (T5), XCD-aware block swizzle (T1).

typedef __attribute__((ext_vector_type(8))) __bf16 bf16x8;
typedef __attribute__((ext_vector_type(4))) float f32x4;
typedef __attribute__((ext_vector_type(4))) unsigned int u32x4;

#define FP8_MAX 448.0f
#define TINY 5.9604644775390625e-8f   // 2^-24

__device__ __forceinline__ void gload_lds16(const void* g, void* l) {
  __builtin_amdgcn_global_load_lds(
      (__attribute__((address_space(1))) void*)g,
      (__attribute__((address_space(3))) void*)l, 16, 0, 0);
}

// ---------------- amax ----------------
__global__ __launch_bounds__(256) void amax_kernel(
    const float* __restrict__ in, long n, unsigned* __restrict__ out) {
  long i0 = (long)blockIdx.x * blockDim.x + threadIdx.x;
  long stride = (long)gridDim.x * blockDim.x;
  long n4 = n >> 2;
  const float4* in4 = (const float4*)in;
  float m = 0.f;
  for (long i = i0; i < n4; i += stride) {
    float4 v = in4[i];
    m = fmaxf(m, fmaxf(fmaxf(fabsf(v.x), fabsf(v.y)),
                       fmaxf(fabsf(v.z), fabsf(v.w))));
  }
  #pragma unroll
  for (int off = 32; off > 0; off >>= 1)
    m = fmaxf(m, __shfl_xor(m, off, 64));
  __shared__ float red[4];
  int lane = threadIdx.x & 63, wid = threadIdx.x >> 6;
  if (lane == 0) red[wid] = m;
  __syncthreads();
  if (threadIdx.x == 0) {
    m = fmaxf(fmaxf(red[0], red[1]), fmaxf(red[2], red[3]));
    atomicMax(out, __float_as_uint(m));  // positive-float bits order-preserving
  }
}

// ---------------- fake-quant to scaled bf16 ----------------
__device__ __forceinline__ unsigned fq1(float x, float s) {
  float xs = x * s;
  xs = fminf(fmaxf(xs, -FP8_MAX), FP8_MAX);
  unsigned u = __float_as_uint(xs);
  unsigned sign = u & 0x80000000u;
  unsigned mag = u & 0x7fffffffu;
  // RNE round mantissa to 3 bits: == round(xs/lsb)*lsb, lsb=2^(floor(log2)-3)
  unsigned r = (mag + 0x7FFFFu + ((mag >> 20) & 1u)) & 0xFFF00000u;
  return (sign | r) >> 16;  // exact bf16 (<=4 mantissa bits)
}

__global__ __launch_bounds__(256) void quant_kernel(
    const float* __restrict__ in, unsigned short* __restrict__ out,
    const unsigned* __restrict__ amaxp, long n) {
  float s = FP8_MAX / fmaxf(__uint_as_float(*amaxp), TINY);
  long i0 = (long)blockIdx.x * blockDim.x + threadIdx.x;
  long stride = (long)gridDim.x * blockDim.x;
  long n8 = n >> 3;
  const float4* in4 = (const float4*)in;
  u32x4* out8 = (u32x4*)out;
  for (long i = i0; i < n8; i += stride) {
    float4 v0 = in4[2 * i];
    float4 v1 = in4[2 * i + 1];
    u32x4 o;
    o.x = fq1(v0.x, s) | (fq1(v0.y, s) << 16);
    o.y = fq1(v0.z, s) | (fq1(v0.w, s) << 16);
    o.z = fq1(v1.x, s) | (fq1(v1.y, s) << 16);
    o.w = fq1(v1.z, s) | (fq1(v1.w, s) << 16);
    out8[i] = o;
  }
}

// ---------------- GEMM ----------------
// C[t,o] = sum_k qx[t,k]*qw[o,k]; epilogue: acc * (ax*aw/448^2) + bias.
// LDS halves: 256 rows x 32 cols bf16 (64B rows); swz: cb ^= (row&3)<<4.
__global__ __launch_bounds__(512, 2) void gemm_kernel(
    const unsigned short* __restrict__ qx, const unsigned short* __restrict__ qw,
    const float* __restrict__ bias, const unsigned* __restrict__ amaxp,
    float* __restrict__ out, int M, int N, int K) {
  __shared__ unsigned short As[2][2][256 * 32];  // [dbuf][khalf]
  __shared__ unsigned short Bs[2][2][256 * 32];

  const int tid = threadIdx.x;
  const int lane = tid & 63;
  const int wid = tid >> 6;
  const int wr = wid >> 2;   // 0..1: wave M-half
  const int wc = wid & 3;    // 0..3: wave N-quarter

  // XCD-aware bijective swizzle (gridDim.x % 8 == 0)
  const int nbn = N >> 8;
  const int cpx = gridDim.x >> 3;
  const int swz = (blockIdx.x & 7) * cpx + (blockIdx.x >> 3);
  const int bm0 = (swz / nbn) << 8;
  const int bn0 = (swz % nbn) << 8;

  f32x4 acc[8][4] = {};

  // ---- staging geometry (per thread): row_j = j*128 + (tid>>2)
  const int srow = tid >> 2;
  const int scb = ((tid & 3) * 16) ^ ((srow & 3) << 4);  // pre-swizzled source chunk
  const size_t a_off = (size_t)(bm0 + srow) * K + (scb >> 1);
  const size_t b_off = (size_t)(bn0 + srow) * K + (scb >> 1);
  const size_t jstride = (size_t)128 * K;
  const int ldsb = wid * 1024;  // wave-uniform byte base (+ j*8192)

  // ---- frag-read geometry: row = (lane&15) + 16m (+wave off); chunk XOR
  const int rcb = (((lane >> 4) << 4) ^ ((lane & 3) << 4)) >> 1;  // ushort idx
  const int arb = (wr * 128 + (lane & 15)) * 32 + rcb;
  const int brb = (wc * 64 + (lane & 15)) * 32 + rcb;

#define STAGE(d, kh, kt)                                                   \
  {                                                                        \
    const unsigned short* ga = qx + a_off + (kt) + (kh) * 32;              \
    const unsigned short* gb = qw + b_off + (kt) + (kh) * 32;              \
    char* la = (char*)&As[d][kh][0] + ldsb;                                \
    char* lb = (char*)&Bs[d][kh][0] + ldsb;                                \
    gload_lds16(ga, la);                                                   \
    gload_lds16(ga + jstride, la + 8192);                                  \
    gload_lds16(gb, lb);                                                   \
    gload_lds16(gb + jstride, lb + 8192);                                  \
  }

#define PHASE(d, kh)                                                       \
  {                                                                        \
    bf16x8 a[8], b[4];                                                     \
    _Pragma("unroll")                                                      \
    for (int m = 0; m < 8; ++m)                                            \
      a[m] = __builtin_bit_cast(bf16x8,                                    \
                *(const u32x4*)&As[d][kh][arb + m * 512]);                 \
    _Pragma("unroll")                                                      \
    for (int n = 0; n < 4; ++n)                                            \
      b[n] = __builtin_bit_cast(bf16x8,                                    \
                *(const u32x4*)&Bs[d][kh][brb + n * 512]);                 \
    __builtin_amdgcn_s_setprio(1);                                         \
    _Pragma("unroll")                                                      \
    for (int m = 0; m < 8; ++m)                                            \
      _Pragma("unroll")                                                    \
      for (int n = 0; n < 4; ++n)                                          \
        acc[m][n] = __builtin_amdgcn_mfma_f32_16x16x32_bf16(               \
            a[m], b[n], acc[m][n], 0, 0, 0);                               \
    __builtin_amdgcn_s_setprio(0);                                         \
  }

  // prologue: stage tile 0 (both K-halves) into buf 0 — 8 loads in flight
  STAGE(0, 0, 0);
  STAGE(0, 1, 0);

  const int nt = K >> 6;
  int cur = 0;
  for (int t = 0; t < nt; ++t) {
    const int ktn = (t + 1 == nt) ? 0 : ((t + 1) << 6);  // wrap: keeps vmcnt uniform
    // phase 0 (k-half 0)
    STAGE(cur ^ 1, 0, ktn);
    asm volatile("s_waitcnt vmcnt(8)" ::: "memory");  // drains this tile's kh0
    __builtin_amdgcn_s_barrier();
    PHASE(cur, 0);
    // phase 1 (k-half 1)
    STAGE(cur ^ 1, 1, ktn);
    asm volatile("s_waitcnt vmcnt(8)" ::: "memory");  // drains this tile's kh1
    __builtin_amdgcn_s_barrier();
    PHASE(cur, 1);
    __builtin_amdgcn_s_barrier();  // tile-end: protect buf[cur] before next stage
    cur ^= 1;
  }

  // epilogue: dequant scale + bias
  const float ax = fmaxf(__uint_as_float(amaxp[0]), TINY);
  const float aw = fmaxf(__uint_as_float(amaxp[1]), TINY);
  const float inv = ax * aw * (1.0f / (FP8_MAX * FP8_MAX));
  const int col0 = bn0 + wc * 64 + (lane & 15);
  const int row0 = bm0 + wr * 128 + ((lane >> 4) << 2);
  #pragma unroll
  for (int n = 0; n < 4; ++n) {
    float bv = bias[col0 + n * 16];
    #pragma unroll
    for (int m = 0; m < 8; ++m)
      #pragma unroll
      for (int j = 0; j < 4; ++j)
        out[(size_t)(row0 + m * 16 + j) * N + col0 + n * 16] =
            acc[m][n][j] * inv + bv;
  }
#undef STAGE
#undef PHASE
}

extern "C" void kernel_launch(void* const* d_in, const int* in_sizes, int n_in,
                              void* d_out, int out_size, void* d_ws, size_t ws_size,
                              hipStream_t stream) {
  const float* x = (const float*)d_in[0];
  const float* w = (const float*)d_in[1];
  const float* bias = (const float*)d_in[2];
  float* out = (float*)d_out;

  long nx = in_sizes[0];
  long nw = in_sizes[1];
  int N = in_sizes[2];          // 16384
  int K = (int)(nw / N);        // 4096
  int M = (int)(nx / K);        // 4096

  unsigned* amax = (unsigned*)d_ws;
  unsigned short* qx = (unsigned short*)((char*)d_ws + 256);
  unsigned short* qw = (unsigned short*)((char*)d_ws + 256 + (size_t)M * K * 2);

  hipMemsetAsync(d_ws, 0, 256, stream);
  amax_kernel<<<2048, 256, 0, stream>>>(x, nx, amax + 0);
  amax_kernel<<<2048, 256, 0, stream>>>(w, nw, amax + 1);
  quant_kernel<<<4096, 256, 0, stream>>>(x, qx, amax + 0, nx);
  quant_kernel<<<4096, 256, 0, stream>>>(w, qw, amax + 1, nw);

  int nwg = (M >> 8) * (N >> 8);   // 16*64 = 1024, %8==0
  gemm_kernel<<<nwg, 512, 0, stream>>>(qx, qw, bias, amax, out, M, N, K);
}

// Round 4
// 1106.993 us; speedup vs baseline: 1.0930x; 1.0930x over previous
//
#include <hip/hip_runtime.h>
#include <hip/hip_bf16.h>

// QuantizedLinear: fp8-e4m3 fake-quant (dynamic per-tensor scale) of x and W,
// then out = qx @ qW^T + bias.
//
// Stage 1: fused amax(x), amax(w) via atomicMax on float bits (one kernel).
// Stage 2: fused quant of x and w to SCALED bf16 (exact: <=4 mantissa bits
//          after RNE-to-3-bit mantissa rounding == round(xs/lsb)*lsb).
//          Dequant by amax_x*amax_w/448^2 deferred to GEMM epilogue.
// Stage 3: GEMM 256x256 tile, BK=64 in two 32-k phases, 8 waves (2x4),
//          double-buffered LDS (128 KiB), counted s_waitcnt vmcnt(8) (T4),
//          conflict-free chunk swizzle c ^= (row>>1)&3 on 16B chunks (T2;
//          row bit0 already selects the 64B half of the 128B bank window,
//          so only row bits 1-2 decorrelate banks), setprio (T5), XCD
//          swizzle (T1). 2 barriers per K-tile.

typedef __attribute__((ext_vector_type(8))) __bf16 bf16x8;
typedef __attribute__((ext_vector_type(4))) float f32x4;
typedef __attribute__((ext_vector_type(4))) unsigned int u32x4;

#define FP8_MAX 448.0f
#define TINY 5.9604644775390625e-8f   // 2^-24

__device__ __forceinline__ void gload_lds16(const void* g, void* l) {
  __builtin_amdgcn_global_load_lds(
      (__attribute__((address_space(1))) void*)g,
      (__attribute__((address_space(3))) void*)l, 16, 0, 0);
}

// ---------------- fused amax (x: blocks [0,512), w: rest) ----------------
__global__ __launch_bounds__(256) void amax_kernel(
    const float* __restrict__ x, long nx, const float* __restrict__ w, long nw,
    unsigned* __restrict__ out) {
  const int xblocks = 512;
  const float* in;
  long n4;
  int bid, nb, slot;
  if (blockIdx.x < xblocks) {
    in = x; n4 = nx >> 2; bid = blockIdx.x; nb = xblocks; slot = 0;
  } else {
    in = w; n4 = nw >> 2; bid = blockIdx.x - xblocks; nb = gridDim.x - xblocks; slot = 1;
  }
  long i0 = (long)bid * blockDim.x + threadIdx.x;
  long stride = (long)nb * blockDim.x;
  const float4* in4 = (const float4*)in;
  float m = 0.f;
  for (long i = i0; i < n4; i += stride) {
    float4 v = in4[i];
    m = fmaxf(m, fmaxf(fmaxf(fabsf(v.x), fabsf(v.y)),
                       fmaxf(fabsf(v.z), fabsf(v.w))));
  }
  #pragma unroll
  for (int off = 32; off > 0; off >>= 1)
    m = fmaxf(m, __shfl_xor(m, off, 64));
  __shared__ float red[4];
  int lane = threadIdx.x & 63, wid = threadIdx.x >> 6;
  if (lane == 0) red[wid] = m;
  __syncthreads();
  if (threadIdx.x == 0) {
    m = fmaxf(fmaxf(red[0], red[1]), fmaxf(red[2], red[3]));
    atomicMax(out + slot, __float_as_uint(m));  // positive floats: bit order == value order
  }
}

// ---------------- fused fake-quant to scaled bf16 ----------------
__device__ __forceinline__ unsigned fq1(float x, float s) {
  float xs = x * s;
  xs = fminf(fmaxf(xs, -FP8_MAX), FP8_MAX);
  unsigned u = __float_as_uint(xs);
  unsigned sign = u & 0x80000000u;
  unsigned mag = u & 0x7fffffffu;
  // RNE round mantissa to 3 bits: == round(xs/lsb)*lsb, lsb=2^(floor(log2)-3)
  unsigned r = (mag + 0x7FFFFu + ((mag >> 20) & 1u)) & 0xFFF00000u;
  return (sign | r) >> 16;  // exact bf16 (<=4 mantissa bits)
}

__global__ __launch_bounds__(256) void quant_kernel(
    const float* __restrict__ x, unsigned short* __restrict__ qx, long nx,
    const float* __restrict__ w, unsigned short* __restrict__ qw, long nw,
    const unsigned* __restrict__ amaxp) {
  const int xblocks = 1024;
  const float* in; unsigned short* out; long n8; int bid, nb, slot;
  if (blockIdx.x < xblocks) {
    in = x; out = qx; n8 = nx >> 3; bid = blockIdx.x; nb = xblocks; slot = 0;
  } else {
    in = w; out = qw; n8 = nw >> 3; bid = blockIdx.x - xblocks;
    nb = gridDim.x - xblocks; slot = 1;
  }
  float s = FP8_MAX / fmaxf(__uint_as_float(amaxp[slot]), TINY);
  long i0 = (long)bid * blockDim.x + threadIdx.x;
  long stride = (long)nb * blockDim.x;
  const float4* in4 = (const float4*)in;
  u32x4* out8 = (u32x4*)out;
  for (long i = i0; i < n8; i += stride) {
    float4 v0 = in4[2 * i];
    float4 v1 = in4[2 * i + 1];
    u32x4 o;
    o.x = fq1(v0.x, s) | (fq1(v0.y, s) << 16);
    o.y = fq1(v0.z, s) | (fq1(v0.w, s) << 16);
    o.z = fq1(v1.x, s) | (fq1(v1.y, s) << 16);
    o.w = fq1(v1.z, s) | (fq1(v1.w, s) << 16);
    out8[i] = o;
  }
}

// ---------------- GEMM ----------------
// C[t,o] = sum_k qx[t,k]*qw[o,k]; epilogue: acc * (ax*aw/448^2) + bias.
// LDS halves: 256 rows x 32 cols bf16 (64B rows, 4x16B chunks);
// chunk swizzle: c ^= (row>>1)&3  (conflict-free, see header).
__global__ __launch_bounds__(512, 2) void gemm_kernel(
    const unsigned short* __restrict__ qx, const unsigned short* __restrict__ qw,
    const float* __restrict__ bias, const unsigned* __restrict__ amaxp,
    float* __restrict__ out, int M, int N, int K) {
  __shared__ unsigned short As[2][2][256 * 32];  // [dbuf][khalf]
  __shared__ unsigned short Bs[2][2][256 * 32];

  const int tid = threadIdx.x;
  const int lane = tid & 63;
  const int wid = tid >> 6;
  const int wr = wid >> 2;   // 0..1: wave M-half
  const int wc = wid & 3;    // 0..3: wave N-quarter

  // XCD-aware bijective swizzle (gridDim.x % 8 == 0)
  const int nbn = N >> 8;
  const int cpx = gridDim.x >> 3;
  const int swz = (blockIdx.x & 7) * cpx + (blockIdx.x >> 3);
  const int bm0 = (swz / nbn) << 8;
  const int bn0 = (swz % nbn) << 8;

  f32x4 acc[8][4] = {};

  // ---- staging geometry (per thread): row = tid>>2 (+128 for j=1)
  const int srow = tid >> 2;
  const int scb = ((tid & 3) ^ ((srow >> 1) & 3)) << 4;  // pre-swizzled src chunk (bytes)
  const size_t a_off = (size_t)(bm0 + srow) * K + (scb >> 1);
  const size_t b_off = (size_t)(bn0 + srow) * K + (scb >> 1);
  const size_t jstride = (size_t)128 * K;
  const int ldsb = wid * 1024;  // wave-uniform byte base (+ j*8192)

  // ---- frag-read geometry: row = (lane&15) + 16m (+wave off)
  // phys chunk = logical chunk (lane>>4) ^ ((row>>1)&3); row>>1&3 == lane>>1&3
  const int rcb = ((((lane >> 4) ^ ((lane >> 1) & 3)) << 4) >> 1);  // ushort idx
  const int arb = (wr * 128 + (lane & 15)) * 32 + rcb;
  const int brb = (wc * 64 + (lane & 15)) * 32 + rcb;

#define STAGE(d, kh, kt)                                                   \
  {                                                                        \
    const unsigned short* ga = qx + a_off + (kt) + (kh) * 32;              \
    const unsigned short* gb = qw + b_off + (kt) + (kh) * 32;              \
    char* la = (char*)&As[d][kh][0] + ldsb;                                \
    char* lb = (char*)&Bs[d][kh][0] + ldsb;                                \
    gload_lds16(ga, la);                                                   \
    gload_lds16(ga + jstride, la + 8192);                                  \
    gload_lds16(gb, lb);                                                   \
    gload_lds16(gb + jstride, lb + 8192);                                  \
  }

#define PHASE(d, kh)                                                       \
  {                                                                        \
    bf16x8 a[8], b[4];                                                     \
    _Pragma("unroll")                                                      \
    for (int m = 0; m < 8; ++m)                                            \
      a[m] = __builtin_bit_cast(bf16x8,                                    \
                *(const u32x4*)&As[d][kh][arb + m * 512]);                 \
    _Pragma("unroll")                                                      \
    for (int n = 0; n < 4; ++n)                                            \
      b[n] = __builtin_bit_cast(bf16x8,                                    \
                *(const u32x4*)&Bs[d][kh][brb + n * 512]);                 \
    __builtin_amdgcn_s_setprio(1);                                         \
    _Pragma("unroll")                                                      \
    for (int m = 0; m < 8; ++m)                                            \
      _Pragma("unroll")                                                    \
      for (int n = 0; n < 4; ++n)                                          \
        acc[m][n] = __builtin_amdgcn_mfma_f32_16x16x32_bf16(               \
            a[m], b[n], acc[m][n], 0, 0, 0);                               \
    __builtin_amdgcn_s_setprio(0);                                         \
  }

  // prologue: stage tile 0 (both K-halves) into buf 0 — 8 loads in flight
  STAGE(0, 0, 0);
  STAGE(0, 1, 0);

  const int nt = K >> 6;
  int cur = 0;
  for (int t = 0; t < nt; ++t) {
    const int ktn = (t + 1 == nt) ? 0 : ((t + 1) << 6);  // wrap keeps vmcnt uniform
    // phase 0 (k-half 0): 12 in flight, wait to 8 == this tile's kh0 done
    STAGE(cur ^ 1, 0, ktn);
    asm volatile("s_waitcnt vmcnt(8)" ::: "memory");
    __builtin_amdgcn_s_barrier();
    PHASE(cur, 0);
    // phase 1 (k-half 1)
    STAGE(cur ^ 1, 1, ktn);
    asm volatile("s_waitcnt vmcnt(8)" ::: "memory");
    __builtin_amdgcn_s_barrier();
    PHASE(cur, 1);
    // no tile-end barrier: buf[cur][0]'s reads completed before barrier 2,
    // so next iteration's STAGE into it cannot race; kh1 readers are
    // protected by next iteration's barrier 1.
    cur ^= 1;
  }

  // epilogue: dequant scale + bias
  const float ax = fmaxf(__uint_as_float(amaxp[0]), TINY);
  const float aw = fmaxf(__uint_as_float(amaxp[1]), TINY);
  const float inv = ax * aw * (1.0f / (FP8_MAX * FP8_MAX));
  const int col0 = bn0 + wc * 64 + (lane & 15);
  const int row0 = bm0 + wr * 128 + ((lane >> 4) << 2);
  #pragma unroll
  for (int n = 0; n < 4; ++n) {
    float bv = bias[col0 + n * 16];
    #pragma unroll
    for (int m = 0; m < 8; ++m)
      #pragma unroll
      for (int j = 0; j < 4; ++j)
        out[(size_t)(row0 + m * 16 + j) * N + col0 + n * 16] =
            acc[m][n][j] * inv + bv;
  }
#undef STAGE
#undef PHASE
}

extern "C" void kernel_launch(void* const* d_in, const int* in_sizes, int n_in,
                              void* d_out, int out_size, void* d_ws, size_t ws_size,
                              hipStream_t stream) {
  const float* x = (const float*)d_in[0];
  const float* w = (const float*)d_in[1];
  const float* bias = (const float*)d_in[2];
  float* out = (float*)d_out;

  long nx = in_sizes[0];
  long nw = in_sizes[1];
  int N = in_sizes[2];          // 16384
  int K = (int)(nw / N);        // 4096
  int M = (int)(nx / K);        // 4096

  unsigned* amax = (unsigned*)d_ws;
  unsigned short* qx = (unsigned short*)((char*)d_ws + 256);
  unsigned short* qw = (unsigned short*)((char*)d_ws + 256 + (size_t)M * K * 2);

  hipMemsetAsync(d_ws, 0, 256, stream);
  amax_kernel<<<2560, 256, 0, stream>>>(x, nx, w, nw, amax);
  quant_kernel<<<5120, 256, 0, stream>>>(x, qx, nx, w, qw, nw, amax);

  int nwg = (M >> 8) * (N >> 8);   // 16*64 = 1024, %8==0
  gemm_kernel<<<nwg, 512, 0, stream>>>(qx, qw, bias, amax, out, M, N, K);
}